// Round 1
// baseline (647.059 us; speedup 1.0000x reference)
//
#include <hip/hip_runtime.h>
#include <hip/hip_bf16.h>
#include <stdint.h>

typedef __bf16 bf16_t;
typedef __bf16 bf16x8 __attribute__((ext_vector_type(8)));
typedef float f32x4 __attribute__((ext_vector_type(4)));

#define BB 4
#define NN 4096
#define DD 384
#define KBLK 32
#define NKT (NN / KBLK)            // 128 kv tiles
#define LOG2E_OVER_T 20.609929155556627f   // log2(e)/0.07

// ---------------- Kernel 1: row-normalize -> bf16 ----------------
__global__ __launch_bounds__(256) void norm_kernel(const float* __restrict__ x,
                                                   bf16_t* __restrict__ xn) {
    int row  = blockIdx.x * 4 + (threadIdx.x >> 6);
    int lane = threadIdx.x & 63;
    const float* xr = x + (size_t)row * DD;
    float v[6];
    float ss = 0.f;
#pragma unroll
    for (int j = 0; j < 6; ++j) { v[j] = xr[lane + j * 64]; ss += v[j] * v[j]; }
#pragma unroll
    for (int m = 1; m < 64; m <<= 1) ss += __shfl_xor(ss, m);
    float inv = 1.0f / fmaxf(sqrtf(ss), 1e-12f);
    bf16_t* o = xn + (size_t)row * DD;
#pragma unroll
    for (int j = 0; j < 6; ++j) o[lane + j * 64] = (bf16_t)(v[j] * inv);
}

// ---------------- Kernel 2: transpose-cast x -> xvT (B, D, N) bf16 ----------------
__global__ __launch_bounds__(256) void transpose_kernel(const float* __restrict__ x,
                                                        bf16_t* __restrict__ xvT) {
    // 64(n) x 64(d) tiles
    int bid = blockIdx.x;
    int dt = bid % (DD / 64);                 // 6
    int nt = (bid / (DD / 64)) % (NN / 64);   // 64
    int b  = bid / ((DD / 64) * (NN / 64));
    __shared__ float tile[64][65];
    int t = threadIdx.x;
    const float* src = x + ((size_t)b * NN + (size_t)nt * 64) * DD + dt * 64;
#pragma unroll
    for (int j = 0; j < 4; ++j) {
        int lin = j * 256 + t;
        int nl = lin >> 4;
        int dc = (lin & 15) * 4;
        const float4 f = *(const float4*)(src + (size_t)nl * DD + dc);
        tile[nl][dc + 0] = f.x; tile[nl][dc + 1] = f.y;
        tile[nl][dc + 2] = f.z; tile[nl][dc + 3] = f.w;
    }
    __syncthreads();
    bf16_t* dst = xvT + ((size_t)b * DD + (size_t)dt * 64) * NN + (size_t)nt * 64;
#pragma unroll
    for (int j = 0; j < 2; ++j) {
        int lin = j * 256 + t;
        int dl = lin >> 3;
        int nc = (lin & 7) * 8;
        bf16x8 v;
#pragma unroll
        for (int jj = 0; jj < 8; ++jj) v[jj] = (bf16_t)tile[nc + jj][dl];
        *(bf16x8*)(dst + (size_t)dl * NN + nc) = v;
    }
}

__device__ __forceinline__ void load_lds16(const void* g, void* l) {
    __builtin_amdgcn_global_load_lds((const __attribute__((address_space(1))) uint32_t*)g,
                                     (__attribute__((address_space(3))) uint32_t*)l,
                                     16, 0, 0);
}

// ---------------- Kernel 3: flash attention + residual ----------------
__global__ __launch_bounds__(256, 2) void attn_kernel(const float* __restrict__ x,
                                                      const bf16_t* __restrict__ xn,
                                                      const bf16_t* __restrict__ xvT,
                                                      float* __restrict__ out) {
    __shared__ bf16_t Ks[KBLK * DD];        // 24 KB, XOR-swizzled layout
    __shared__ bf16_t Pb[4 * 16 * KBLK];    // 4 KB, per-wave P buffer

    const int tid = threadIdx.x;
    const int w = tid >> 6, l = tid & 63;
    const int lo = l & 15, g = l >> 4;

    // XCD-aware mapping: batch = (bid>>1)&3 so each batch's K/V stream sits on 2 XCDs
    const int bid = blockIdx.x;
    const int b  = (bid >> 1) & 3;
    const int qt = (bid >> 3) | ((bid & 1) << 5);

    // --- Q fragments in registers (12 chunks of K=32) ---
    const size_t qrow = (size_t)b * NN + (size_t)qt * 64 + w * 16 + lo;
    const bf16_t* qp = xn + qrow * DD + g * 8;
    bf16x8 qf[12];
#pragma unroll
    for (int c = 0; c < 12; ++c) qf[c] = *(const bf16x8*)(qp + c * 32);

    const f32x4 fzero = {0.f, 0.f, 0.f, 0.f};
    f32x4 O[24];
#pragma unroll
    for (int i = 0; i < 24; ++i) O[i] = fzero;
    float m[4]    = {-1e30f, -1e30f, -1e30f, -1e30f};
    float lsum[4] = {0.f, 0.f, 0.f, 0.f};

    // B-fragment (K) read bases: key*rowbytes, swizzle key-dependent
    int keyb[2], swz[2];
#pragma unroll
    for (int nt = 0; nt < 2; ++nt) {
        int key  = nt * 16 + lo;
        keyb[nt] = key * (DD * 2);
        swz[nt]  = (key & 7) << 4;
    }
    const int off16 = g * 16;

    const char* xnb  = (const char*)xn;
    const char* Ksb  = (const char*)Ks;
    bf16_t* Pw       = Pb + w * 16 * KBLK;
    const bf16_t* pap = Pw + lo * KBLK + g * 8;

    // V per-lane byte base in xvT
    const char* vb = (const char*)xvT + ((((size_t)b * DD + lo) * NN) + g * 8) * 2;

    // staging: per-thread (row, swizzled col) for 6 chunks of 16B
    for (int kt = 0; kt < NKT; ++kt) {
        __syncthreads();   // protect Ks from overwrite while prior QK reads in flight
        const size_t gbase = ((size_t)b * NN + (size_t)kt * KBLK) * (DD * 2);
#pragma unroll
        for (int i = 0; i < 6; ++i) {
            int id  = i * 256 + tid;
            int row = id / 48;
            int cb  = (id % 48) * 16;
            const char* gp = xnb + gbase + (size_t)row * (DD * 2) + (cb ^ ((row & 7) << 4));
            load_lds16(gp, (void*)(Ksb + (size_t)(i * 256 + (w << 6)) * 16));
        }
        __syncthreads();   // implied vmcnt(0) drain completes global_load_lds

        // --- QK^T: S (16 q x 32 k), 24 MFMAs ---
        f32x4 s[2]; s[0] = fzero; s[1] = fzero;
#pragma unroll
        for (int c = 0; c < 12; ++c) {
#pragma unroll
            for (int nt = 0; nt < 2; ++nt) {
                bf16x8 kf = *(const bf16x8*)(Ksb + keyb[nt] + ((c * 64 + off16) ^ swz[nt]));
                s[nt] = __builtin_amdgcn_mfma_f32_16x16x32_bf16(qf[c], kf, s[nt], 0, 0, 0);
            }
        }

        // --- online softmax (log2 domain) ---
        float rm[4], p0[4], p1[4], rs[4];
#pragma unroll
        for (int r = 0; r < 4; ++r) {
            s[0][r] *= LOG2E_OVER_T;
            s[1][r] *= LOG2E_OVER_T;
            rm[r] = fmaxf(s[0][r], s[1][r]);
        }
#pragma unroll
        for (int mk = 1; mk < 16; mk <<= 1) {
#pragma unroll
            for (int r = 0; r < 4; ++r) rm[r] = fmaxf(rm[r], __shfl_xor(rm[r], mk));
        }
        bool changed = (rm[0] > m[0]) | (rm[1] > m[1]) | (rm[2] > m[2]) | (rm[3] > m[3]);
        if (__any(changed)) {
            float scl[4];
#pragma unroll
            for (int r = 0; r < 4; ++r) {
                float mn = fmaxf(m[r], rm[r]);
                scl[r] = exp2f(m[r] - mn);
                m[r] = mn;
                lsum[r] *= scl[r];
            }
#pragma unroll
            for (int i = 0; i < 24; ++i) {
                O[i][0] *= scl[0]; O[i][1] *= scl[1];
                O[i][2] *= scl[2]; O[i][3] *= scl[3];
            }
        }
#pragma unroll
        for (int r = 0; r < 4; ++r) {
            p0[r] = exp2f(s[0][r] - m[r]);
            p1[r] = exp2f(s[1][r] - m[r]);
            rs[r] = p0[r] + p1[r];
        }
#pragma unroll
        for (int mk = 1; mk < 16; mk <<= 1) {
#pragma unroll
            for (int r = 0; r < 4; ++r) rs[r] += __shfl_xor(rs[r], mk);
        }
#pragma unroll
        for (int r = 0; r < 4; ++r) lsum[r] += rs[r];

        // --- P -> LDS (C-layout scatter), read back as A-fragment ---
#pragma unroll
        for (int r = 0; r < 4; ++r) {
            Pw[(g * 4 + r) * KBLK + lo]      = (bf16_t)p0[r];
            Pw[(g * 4 + r) * KBLK + lo + 16] = (bf16_t)p1[r];
        }
        bf16x8 pa = *(const bf16x8*)pap;

        // --- PV: O (16 q x 384 d), 24 MFMAs, V direct from global (L2) ---
        const char* vp = vb + (size_t)kt * (KBLK * 2);
#pragma unroll
        for (int dt = 0; dt < 24; ++dt) {
            bf16x8 vf = *(const bf16x8*)(vp + (size_t)dt * 16 * NN * 2);
            O[dt] = __builtin_amdgcn_mfma_f32_16x16x32_bf16(pa, vf, O[dt], 0, 0, 0);
        }
    }

    // --- epilogue: out = x + 0.3 * O / l ---
    float li[4];
#pragma unroll
    for (int r = 0; r < 4; ++r) li[r] = 0.3f / lsum[r];
    const size_t orow0 = (size_t)b * NN + (size_t)qt * 64 + w * 16;
#pragma unroll
    for (int dt = 0; dt < 24; ++dt) {
#pragma unroll
        for (int r = 0; r < 4; ++r) {
            size_t idx = (orow0 + g * 4 + r) * DD + dt * 16 + lo;
            out[idx] = x[idx] + O[dt][r] * li[r];
        }
    }
}

extern "C" void kernel_launch(void* const* d_in, const int* in_sizes, int n_in,
                              void* d_out, int out_size, void* d_ws, size_t ws_size,
                              hipStream_t stream) {
    const float* x = (const float*)d_in[0];
    float* out = (float*)d_out;
    bf16_t* xn  = (bf16_t*)d_ws;
    bf16_t* xvT = xn + (size_t)BB * NN * DD;

    norm_kernel<<<(BB * NN) / 4, 256, 0, stream>>>(x, xn);
    transpose_kernel<<<BB * (NN / 64) * (DD / 64), 256, 0, stream>>>(x, xvT);
    attn_kernel<<<256, 256, 0, stream>>>(x, xn, xvT, out);
}

// Round 2
// 277.713 us; speedup vs baseline: 2.3300x; 2.3300x over previous
//
#include <hip/hip_runtime.h>
#include <hip/hip_bf16.h>
#include <stdint.h>

typedef __bf16 bf16_t;
typedef __bf16 bf16x8 __attribute__((ext_vector_type(8)));
typedef float f32x4 __attribute__((ext_vector_type(4)));

#define BB 4
#define NN 4096
#define DD 384
#define KBLK 32
#define NKT (NN / KBLK)            // 128 kv tiles
#define NROWS (BB * NN)            // 16384
#define SCALEC 20.609929155556627f // log2(e)/0.07 ; also the fixed softmax max

// ---------------- Kernel 1: row-normalize -> bf16 ----------------
__global__ __launch_bounds__(256) void norm_kernel(const float* __restrict__ x,
                                                   bf16_t* __restrict__ xn) {
    int row  = blockIdx.x * 4 + (threadIdx.x >> 6);
    int lane = threadIdx.x & 63;
    const float* xr = x + (size_t)row * DD;
    float v[6];
    float ss = 0.f;
#pragma unroll
    for (int j = 0; j < 6; ++j) { v[j] = xr[lane + j * 64]; ss += v[j] * v[j]; }
#pragma unroll
    for (int m = 1; m < 64; m <<= 1) ss += __shfl_xor(ss, m);
    float inv = 1.0f / fmaxf(sqrtf(ss), 1e-12f);
    bf16_t* o = xn + (size_t)row * DD;
#pragma unroll
    for (int j = 0; j < 6; ++j) o[lane + j * 64] = (bf16_t)(v[j] * inv);
}

// ---------------- Kernel 2: transpose-cast x -> xvT (B, D, N) bf16 ----------------
__global__ __launch_bounds__(256) void transpose_kernel(const float* __restrict__ x,
                                                        bf16_t* __restrict__ xvT) {
    int bid = blockIdx.x;
    int dt = bid % (DD / 64);                 // 6
    int nt = (bid / (DD / 64)) % (NN / 64);   // 64
    int b  = bid / ((DD / 64) * (NN / 64));
    __shared__ float tile[64][65];
    int t = threadIdx.x;
    const float* src = x + ((size_t)b * NN + (size_t)nt * 64) * DD + dt * 64;
#pragma unroll
    for (int j = 0; j < 4; ++j) {
        int lin = j * 256 + t;
        int nl = lin >> 4;
        int dc = (lin & 15) * 4;
        const float4 f = *(const float4*)(src + (size_t)nl * DD + dc);
        tile[nl][dc + 0] = f.x; tile[nl][dc + 1] = f.y;
        tile[nl][dc + 2] = f.z; tile[nl][dc + 3] = f.w;
    }
    __syncthreads();
    bf16_t* dst = xvT + ((size_t)b * DD + (size_t)dt * 64) * NN + (size_t)nt * 64;
#pragma unroll
    for (int j = 0; j < 2; ++j) {
        int lin = j * 256 + t;
        int dl = lin >> 3;
        int nc = (lin & 7) * 8;
        bf16x8 v;
#pragma unroll
        for (int jj = 0; jj < 8; ++jj) v[jj] = (bf16_t)tile[nc + jj][dl];
        *(bf16x8*)(dst + (size_t)dl * NN + nc) = v;
    }
}

__device__ __forceinline__ void load_lds16(const void* g, void* l) {
    __builtin_amdgcn_global_load_lds((const __attribute__((address_space(1))) uint32_t*)g,
                                     (__attribute__((address_space(3))) uint32_t*)l,
                                     16, 0, 0);
}

// ---------------- Kernel 3: flash attention, fixed-max softmax, KV-split ----------------
// LDS layouts are fragment-linear (chunk-major):
//   K buf: slot ci = (c*4+g)*32 + nt*16 + lo  -> holds xn[key=nt*16+lo][elems (c*4+g)*8..+8]
//   V buf: slot ci = (dt*4+g)*16 + lo         -> holds xvT[d=dt*16+lo][keys g*8..+8]
// so every ds_read_b128 fragment fetch is contiguous across the 64 lanes (0 conflicts).
template <int S, bool DIRECT>
__global__ __launch_bounds__(256, 2) void attn_kernel(const float* __restrict__ x,
                                                      const bf16_t* __restrict__ xn,
                                                      const bf16_t* __restrict__ xvT,
                                                      float* __restrict__ out,
                                                      float* __restrict__ Opart,
                                                      float* __restrict__ lpart) {
    constexpr int TPS = NKT / S;   // tiles per split
    __shared__ __align__(16) char Ks[2][24576];   // K double buffer
    __shared__ __align__(16) char VL[24576];      // V shared tile
    __shared__ __align__(16) bf16_t Pb[4 * 16 * KBLK];

    const int tid = threadIdx.x;
    const int w = tid >> 6, l = tid & 63;
    const int lo = l & 15, g = l >> 4;

    const int bid = blockIdx.x;
    const int s_idx = (S == 2) ? (bid & 1) : 0;
    const int qbid  = (S == 2) ? (bid >> 1) : bid;
    const int b  = (qbid >> 1) & 3;
    const int qt = (qbid >> 3) | ((qbid & 1) << 5);
    const int kt0 = s_idx * TPS;

    // --- Q fragments in registers (12 chunks of K=32) ---
    const size_t qrow = (size_t)b * NN + (size_t)qt * 64 + w * 16 + lo;
    const bf16_t* qp = xn + qrow * DD + g * 8;
    bf16x8 qf[12];
#pragma unroll
    for (int c = 0; c < 12; ++c) qf[c] = *(const bf16x8*)(qp + c * 32);

    const f32x4 fzero = {0.f, 0.f, 0.f, 0.f};
    f32x4 O[24];
#pragma unroll
    for (int i = 0; i < 24; ++i) O[i] = fzero;
    float lacc[4] = {0.f, 0.f, 0.f, 0.f};

    const char* xnb  = (const char*)xn;
    const char* xvTb = (const char*)xvT;
    char* Ksb = (char*)Ks;
    char* VLb = (char*)VL;
    bf16_t* Pw = Pb + w * 16 * KBLK;

    // --- prologue: stage K[kt0] into buf 0 ---
    {
        const size_t kgbase = ((size_t)b * NN + (size_t)kt0 * KBLK) * (DD * 2);
#pragma unroll
        for (int i = 0; i < 6; ++i) {
            int ci = i * 256 + tid;
            int key = ci & 31, cg = ci >> 5;
            const char* gp = xnb + kgbase + key * (DD * 2) + cg * 16;
            load_lds16(gp, (void*)(Ksb + (i * 256 + (w << 6)) * 16));
        }
    }
    __syncthreads();

    for (int t = 0; t < TPS; ++t) {
        const int p = t & 1;
        const int kt = kt0 + t;
        // --- issue V[t] stage (oldest 6 vmem ops of this wave) ---
        {
            const size_t vgbase = (size_t)b * ((size_t)DD * NN * 2) + (size_t)kt * (KBLK * 2);
#pragma unroll
            for (int i = 0; i < 6; ++i) {
                int ci = i * 256 + tid;
                int lo4 = ci & 15, g4 = (ci >> 4) & 3, dt = ci >> 6;
                const char* gp = xvTb + vgbase + (size_t)(dt * 16 + lo4) * (NN * 2) + g4 * 16;
                load_lds16(gp, (void*)(VLb + (i * 256 + (w << 6)) * 16));
            }
        }
        __builtin_amdgcn_sched_barrier(0);
        // --- issue K[t+1] stage into other buffer (reads 1 tile past split end: safe, in-ws) ---
        {
            const size_t kgbase = ((size_t)b * NN + (size_t)(kt + 1) * KBLK) * (DD * 2);
            char* Kdst = Ksb + (p ^ 1) * 24576;
#pragma unroll
            for (int i = 0; i < 6; ++i) {
                int ci = i * 256 + tid;
                int key = ci & 31, cg = ci >> 5;
                const char* gp = xnb + kgbase + key * (DD * 2) + cg * 16;
                load_lds16(gp, (void*)(Kdst + (i * 256 + (w << 6)) * 16));
            }
        }
        __builtin_amdgcn_sched_barrier(0);

        // --- QK^T from K buf p: 24 MFMAs, contiguous b128 reads ---
        const char* kb = Ksb + p * 24576 + (g << 9) + (lo << 4);
        f32x4 s0 = fzero, s1 = fzero;
#pragma unroll
        for (int c = 0; c < 12; ++c) {
            bf16x8 kf0 = *(const bf16x8*)(kb + c * 2048);
            bf16x8 kf1 = *(const bf16x8*)(kb + c * 2048 + 256);
            s0 = __builtin_amdgcn_mfma_f32_16x16x32_bf16(qf[c], kf0, s0, 0, 0, 0);
            s1 = __builtin_amdgcn_mfma_f32_16x16x32_bf16(qf[c], kf1, s1, 0, 0, 0);
        }

        // --- fixed-max softmax: p = exp2(s*SCALE - SCALE); no trees, no rescale ---
        float p0[4], p1[4];
#pragma unroll
        for (int r = 0; r < 4; ++r) {
            p0[r] = exp2f(fmaf(s0[r], SCALEC, -SCALEC));
            p1[r] = exp2f(fmaf(s1[r], SCALEC, -SCALEC));
            lacc[r] += p0[r] + p1[r];
        }

        // --- P -> per-wave LDS, read back as A-fragment ---
#pragma unroll
        for (int r = 0; r < 4; ++r) {
            Pw[(g * 4 + r) * KBLK + lo]      = (bf16_t)p0[r];
            Pw[(g * 4 + r) * KBLK + lo + 16] = (bf16_t)p1[r];
        }
        bf16x8 pa = *(const bf16x8*)(Pw + lo * KBLK + g * 8);

        // --- wait for V only (K[t+1] stays in flight), make V visible cross-wave ---
        asm volatile("s_waitcnt vmcnt(6)" ::: "memory");
        __builtin_amdgcn_sched_barrier(0);
        __builtin_amdgcn_s_barrier();
        __builtin_amdgcn_sched_barrier(0);

        // --- PV: 24 MFMAs, contiguous b128 V reads ---
        const char* vbL = VLb + (g << 8) + (lo << 4);
#pragma unroll
        for (int dt = 0; dt < 24; ++dt) {
            bf16x8 vf = *(const bf16x8*)(vbL + dt * 1024);
            O[dt] = __builtin_amdgcn_mfma_f32_16x16x32_bf16(pa, vf, O[dt], 0, 0, 0);
        }
        __syncthreads();   // drains K[t+1] (long done) + protects VL/Ks reuse
    }

    // --- epilogue: reduce denominators once, then store ---
#pragma unroll
    for (int mk = 1; mk < 16; mk <<= 1) {
#pragma unroll
        for (int r = 0; r < 4; ++r) lacc[r] += __shfl_xor(lacc[r], mk);
    }
    const int grow0 = b * NN + qt * 64 + w * 16;   // global row base of this wave
    if (DIRECT) {
        float inv[4];
#pragma unroll
        for (int r = 0; r < 4; ++r) inv[r] = 0.3f / lacc[r];
#pragma unroll
        for (int dt = 0; dt < 24; ++dt) {
#pragma unroll
            for (int r = 0; r < 4; ++r) {
                size_t idx = (size_t)(grow0 + g * 4 + r) * DD + dt * 16 + lo;
                out[idx] = x[idx] + O[dt][r] * inv[r];
            }
        }
    } else {
        float* Ob = Opart + (size_t)s_idx * NROWS * DD;
#pragma unroll
        for (int dt = 0; dt < 24; ++dt) {
#pragma unroll
            for (int r = 0; r < 4; ++r) {
                Ob[(size_t)(grow0 + g * 4 + r) * DD + dt * 16 + lo] = O[dt][r];
            }
        }
        if (lo == 0) {
#pragma unroll
            for (int r = 0; r < 4; ++r)
                lpart[(size_t)s_idx * NROWS + grow0 + g * 4 + r] = lacc[r];
        }
    }
}

// ---------------- Kernel 4: merge 2 splits + residual ----------------
__global__ __launch_bounds__(256) void merge_kernel(const float* __restrict__ x,
                                                    const float* __restrict__ Opart,
                                                    const float* __restrict__ lpart,
                                                    float* __restrict__ out) {
    int row  = blockIdx.x * 4 + (threadIdx.x >> 6);
    int lane = threadIdx.x & 63;
    float lsum = lpart[row] + lpart[NROWS + row];
    float inv = 0.3f / lsum;
    size_t base = (size_t)row * DD;
    const float* O0 = Opart + base;
    const float* O1 = Opart + (size_t)NROWS * DD + base;
#pragma unroll
    for (int j = 0; j < 6; ++j) {
        int d = lane + j * 64;
        out[base + d] = x[base + d] + (O0[d] + O1[d]) * inv;
    }
}

extern "C" void kernel_launch(void* const* d_in, const int* in_sizes, int n_in,
                              void* d_out, int out_size, void* d_ws, size_t ws_size,
                              hipStream_t stream) {
    const float* x = (const float*)d_in[0];
    float* out = (float*)d_out;
    char* ws = (char*)d_ws;

    const size_t xn_bytes = (size_t)BB * NN * DD * 2;           // 12.58 MB
    bf16_t* xn  = (bf16_t*)ws;
    bf16_t* xvT = (bf16_t*)(ws + xn_bytes);
    float* Opart = (float*)(ws + 2 * xn_bytes);
    const size_t Opart_bytes = (size_t)2 * NROWS * DD * 4;      // 50.3 MB
    float* lpart = (float*)(ws + 2 * xn_bytes + Opart_bytes);
    const size_t need2 = 2 * xn_bytes + Opart_bytes + (size_t)2 * NROWS * 4;

    norm_kernel<<<(BB * NN) / 4, 256, 0, stream>>>(x, xn);
    transpose_kernel<<<BB * (NN / 64) * (DD / 64), 256, 0, stream>>>(x, xvT);
    if (ws_size >= need2) {
        attn_kernel<2, false><<<512, 256, 0, stream>>>(x, xn, xvT, out, Opart, lpart);
        merge_kernel<<<NROWS / 4, 256, 0, stream>>>(x, Opart, lpart, out);
    } else {
        attn_kernel<1, true><<<256, 256, 0, stream>>>(x, xn, xvT, out, nullptr, nullptr);
    }
}